// Round 8
// baseline (54.005 us; speedup 1.0000x reference)
//
#include <hip/hip_runtime.h>
#include <hip/hip_bf16.h>

typedef __bf16 bf16x8 __attribute__((ext_vector_type(8)));
typedef float  f32x16 __attribute__((ext_vector_type(16)));

#define NROWS 8192
#define DIM   128
#define NB    64            // 8192 / 128 row-blocks
#define JOBS_PER_MAT 2080   // 64*65/2 upper-tri incl diag

__device__ __forceinline__ float waveReduceSum(float v) {
    for (int off = 32; off; off >>= 1) v += __shfl_xor(v, off, 64);
    return v;
}

__device__ __forceinline__ float fast_exp2(float x) {
    return __builtin_amdgcn_exp2f(x);
}

// async global->LDS, 16B per lane; lds dest is wave-uniform base (+lane*16 by HW)
__device__ __forceinline__ void gload16(const void* g, void* l) {
    __builtin_amdgcn_global_load_lds(
        (const __attribute__((address_space(1))) unsigned int*)(uintptr_t)g,
        (__attribute__((address_space(3))) unsigned int*)(uintptr_t)l,
        16, 0, 0);
}

__device__ __forceinline__ int tri(int b) { return b * NB - (b * (b - 1)) / 2; }

// ---------------------------------------------------------------------------
// Kernel 1: normalize rows (float4, 2 rows/wave), align partials, bf16 copies.
// ---------------------------------------------------------------------------
__global__ __launch_bounds__(256) void prep_kernel(
    const float* __restrict__ users, const float* __restrict__ pos,
    __bf16* __restrict__ Uh, __bf16* __restrict__ Ph,
    double* __restrict__ alignPart)
{
    const int tid  = threadIdx.x;
    const int lane = tid & 63;
    const int w    = tid >> 6;
    const int l32  = lane & 31;
    const int half = lane >> 5;
    const int r    = blockIdx.x * 8 + w * 2 + half;

    const float4 u4 = ((const float4*)users)[r * 32 + l32];
    const float4 p4 = ((const float4*)pos )[r * 32 + l32];

    float su = u4.x*u4.x + u4.y*u4.y + u4.z*u4.z + u4.w*u4.w;
    float sp = p4.x*p4.x + p4.y*p4.y + p4.z*p4.z + p4.w*p4.w;
    for (int off = 16; off; off >>= 1) {
        su += __shfl_xor(su, off, 64);
        sp += __shfl_xor(sp, off, 64);
    }
    const float nu  = fmaxf(sqrtf(su), 1e-12f);
    const float npp = fmaxf(sqrtf(sp), 1e-12f);

    const float ux = u4.x / nu,  uy = u4.y / nu,  uz = u4.z / nu,  uw = u4.w / nu;
    const float px = p4.x / npp, py = p4.y / npp, pz = p4.z / npp, pw = p4.w / npp;

    union { __bf16 h[4]; uint2 q; } cu, cp;
    cu.h[0] = (__bf16)ux; cu.h[1] = (__bf16)uy; cu.h[2] = (__bf16)uz; cu.h[3] = (__bf16)uw;
    cp.h[0] = (__bf16)px; cp.h[1] = (__bf16)py; cp.h[2] = (__bf16)pz; cp.h[3] = (__bf16)pw;
    ((uint2*)Uh)[r * 32 + l32] = cu.q;
    ((uint2*)Ph)[r * 32 + l32] = cp.q;

    const float dx = ux - px, dy = uy - py, dz = uz - pz, dw = uw - pw;
    float al = dx*dx + dy*dy + dz*dz + dw*dw;
    for (int off = 16; off; off >>= 1) al += __shfl_xor(al, off, 64);
    al += __shfl_xor(al, 32, 64);

    __shared__ float wsum[4];
    if (lane == 0) wsum[w] = al;
    __syncthreads();
    if (tid == 0)
        alignPart[blockIdx.x] = (double)wsum[0] + (double)wsum[1]
                              + (double)wsum[2] + (double)wsum[3];
}

// ---------------------------------------------------------------------------
// Kernel 2: 128x128 tile of G = Xn*Xn^T per block (bi<=bj, off-diag x2).
//   4 waves (2x2), wave tile 64x64 via 2x2 mfma_32x32x16 frags (acc f32x16).
//   A-operand: REGISTERS, loaded straight from L2 (a[2][8] = 64 VGPR/lane) —
//   no LDS traffic for A. B-operand: single 32KB LDS buffer [128 rows][16
//   chunks of 16B], whole K staged once per job (2 barriers total).
//   Swizzle: LDS chunk c of row r holds global chunk c^(r&15) (pre-swizzled
//   global source, linear gload_lds dest; reads XOR back).
//   __launch_bounds__(256,3): VGPR<=170 -> 3 blocks/CU; LDS not the cap.
// ---------------------------------------------------------------------------
__global__ __launch_bounds__(256, 3) void gram_kernel(
    const __bf16* __restrict__ Uh, const __bf16* __restrict__ Ph,
    double* __restrict__ Spart)
{
    __shared__ __align__(16) unsigned char smem[32768];
    __shared__ float wsum[4];

    const int bid = blockIdx.x;
    const int mat = bid >= JOBS_PER_MAT;
    const int t   = bid - (mat ? JOBS_PER_MAT : 0);

    int bi = (int)((NB + 0.5f) - sqrtf((NB + 0.5f) * (NB + 0.5f) - 2.0f * (float)t));
    if (bi > 0 && tri(bi) > t) --bi;
    if (tri(bi + 1) <= t) ++bi;
    const int bj = bi + (t - tri(bi));

    const char* __restrict__ Xb = (const char*)(mat ? Ph : Uh);

    const int tid  = threadIdx.x;
    const int lane = tid & 63;
    const int w    = tid >> 6;
    const int wm = w >> 1, wn = w & 1;
    const int l32 = lane & 31;
    const int lh  = lane >> 5;         // k-half within fragment (8 elems each)

    // ---- B staging: thread covers rows (tid>>4)+16p, linear chunk tid&15;
    //      global source chunk pre-swizzled by ^(row&15) = ^(tid>>4). ----
    const int srow  = tid >> 4;
    const int schnk = (tid & 15) ^ srow;
    const char* gB0 = Xb + (size_t)(bj * 128 + srow) * 256 + schnk * 16;
    unsigned char* lB0 = smem + w * 1024;     // wave-uniform dest base

    // issue B staging first (8 passes of 4KB)
#pragma unroll
    for (int p = 0; p < 8; ++p)
        gload16(gB0 + p * 4096, lB0 + p * 4096);

    // ---- A fragments -> registers (16 x dwordx4 from L2, in flight) ----
    const char* aBase = Xb + (size_t)(bi * 128 + wm * 64 + l32) * 256 + lh * 16;
    bf16x8 a[2][8];
#pragma unroll
    for (int mi = 0; mi < 2; ++mi)
#pragma unroll
        for (int ks = 0; ks < 8; ++ks)
            a[mi][ks] = *reinterpret_cast<const bf16x8*>(
                aBase + mi * 32 * 256 + ks * 32);

    f32x16 acc[2][2];
#pragma unroll
    for (int mi = 0; mi < 2; ++mi)
#pragma unroll
        for (int ni = 0; ni < 2; ++ni)
#pragma unroll
            for (int e = 0; e < 16; ++e)
                acc[mi][ni][e] = 0.f;

    __syncthreads();   // B staged (vmcnt(0) drain covers A-loads too)

    // ---- MFMA: 8 K-steps x 2x2 frags; B from LDS, A from regs ----
    const unsigned r0B = (unsigned)(wn * 64 + l32);
#pragma unroll
    for (int ks = 0; ks < 8; ++ks) {
        bf16x8 b[2];
#pragma unroll
        for (int ni = 0; ni < 2; ++ni) {
            const unsigned R = r0B + ni * 32;
            const unsigned c = ((unsigned)(ks * 2 + lh)) ^ (R & 15u);
            b[ni] = *reinterpret_cast<const bf16x8*>(smem + R * 256 + (c << 4));
        }
#pragma unroll
        for (int mi = 0; mi < 2; ++mi)
#pragma unroll
            for (int ni = 0; ni < 2; ++ni)
                acc[mi][ni] = __builtin_amdgcn_mfma_f32_32x32x16_bf16(
                    a[mi][ks], b[ni], acc[mi][ni], 0, 0, 0);
    }

    // ---- epilogue: sum exp2(C1*dot - C1) == exp(-2*d^2) ----
    const float C1 = 4.0f * 1.4426950408889634f;   // 4*log2(e)
    float s0 = 0.f, s1 = 0.f, s2 = 0.f, s3 = 0.f;
#pragma unroll
    for (int mi = 0; mi < 2; ++mi)
#pragma unroll
        for (int ni = 0; ni < 2; ++ni) {
            const f32x16 v = acc[mi][ni];
#pragma unroll
            for (int e = 0; e < 16; e += 4) {
                s0 += fast_exp2(v[e + 0] * C1 - C1);
                s1 += fast_exp2(v[e + 1] * C1 - C1);
                s2 += fast_exp2(v[e + 2] * C1 - C1);
                s3 += fast_exp2(v[e + 3] * C1 - C1);
            }
        }

    const float s = waveReduceSum((s0 + s1) + (s2 + s3));
    if (lane == 0) wsum[w] = s;
    __syncthreads();
    if (tid == 0) {
        double bs = (double)wsum[0] + (double)wsum[1]
                  + (double)wsum[2] + (double)wsum[3];
        if (bi != bj) bs *= 2.0;     // off-diagonal tile counts twice in S_full
        Spart[bid] = bs;
    }
}

// ---------------------------------------------------------------------------
// Kernel 3: final reduction + loss formula. One block, 1024 threads.
// ---------------------------------------------------------------------------
__global__ __launch_bounds__(1024) void finalize_kernel(
    const double* __restrict__ alignPart, const double* __restrict__ Spart,
    float* __restrict__ out)
{
    const int tid = threadIdx.x;
    double a = 0.0, su = 0.0, sp = 0.0;
    for (int i = tid; i < 1024; i += 1024) a += alignPart[i];
    for (int i = tid; i < 2 * JOBS_PER_MAT; i += 1024) {
        const double v = Spart[i];
        if (i < JOBS_PER_MAT) su += v; else sp += v;
    }
    for (int off = 32; off; off >>= 1) {
        a  += __shfl_xor(a,  off, 64);
        su += __shfl_xor(su, off, 64);
        sp += __shfl_xor(sp, off, 64);
    }
    __shared__ double sh[3][16];
    const int lane = tid & 63, wid = tid >> 6;
    if (lane == 0) { sh[0][wid] = a; sh[1][wid] = su; sh[2][wid] = sp; }
    __syncthreads();
    if (tid == 0) {
        double A = 0.0, SU = 0.0, SP = 0.0;
        for (int i = 0; i < 16; ++i) { A += sh[0][i]; SU += sh[1][i]; SP += sh[2][i]; }
        const double Nd = 8192.0;
        const double npairs = Nd * (Nd - 1.0) * 0.5;
        const double align = A / Nd;
        const double mu = (SU - Nd) * 0.5 / npairs;
        const double mp = (SP - Nd) * 0.5 / npairs;
        const double uniform = 0.25 * (log(mu) + log(mp));
        out[0] = (float)((align + uniform) / 8192.0);
    }
}

// ---------------------------------------------------------------------------
extern "C" void kernel_launch(void* const* d_in, const int* in_sizes, int n_in,
                              void* d_out, int out_size, void* d_ws, size_t ws_size,
                              hipStream_t stream)
{
    const float* users = (const float*)d_in[0];
    const float* pos   = (const float*)d_in[1];
    // d_in[2] (neg_items) intentionally unused, matching the reference.
    float* out = (float*)d_out;

    char* ws = (char*)d_ws;
    __bf16* Uh = (__bf16*)ws;                              // 2 MiB
    __bf16* Ph = (__bf16*)(ws + 2097152);                  // 2 MiB
    double* alignPart = (double*)(ws + 4194304);           // 1024 doubles
    double* Spart     = (double*)(ws + 4194304 + 8192);    // 4160 doubles

    hipLaunchKernelGGL(prep_kernel, dim3(1024), dim3(256), 0, stream,
                       users, pos, Uh, Ph, alignPart);
    hipLaunchKernelGGL(gram_kernel, dim3(2 * JOBS_PER_MAT), dim3(256), 0, stream,
                       Uh, Ph, Spart);
    hipLaunchKernelGGL(finalize_kernel, dim3(1), dim3(1024), 0, stream,
                       alignPart, Spart, out);
}

// Round 9
// 33.361 us; speedup vs baseline: 1.6188x; 1.6188x over previous
//
#include <hip/hip_runtime.h>
#include <hip/hip_bf16.h>

typedef int   i32x4  __attribute__((ext_vector_type(4)));
typedef int   i32x16 __attribute__((ext_vector_type(16)));

#define NROWS 8192
#define DIM   128
#define NB    64            // 8192 / 128 row-blocks
#define JOBS_PER_MAT 2080   // 64*65/2 upper-tri incl diag

__device__ __forceinline__ float waveReduceSum(float v) {
    for (int off = 32; off; off >>= 1) v += __shfl_xor(v, off, 64);
    return v;
}

__device__ __forceinline__ float fast_exp2(float x) {
    return __builtin_amdgcn_exp2f(x);
}

// async global->LDS, 16B per lane; lds dest is wave-uniform base (+lane*16 by HW)
__device__ __forceinline__ void gload16(const void* g, void* l) {
    __builtin_amdgcn_global_load_lds(
        (const __attribute__((address_space(1))) unsigned int*)(uintptr_t)g,
        (__attribute__((address_space(3))) unsigned int*)(uintptr_t)l,
        16, 0, 0);
}

__device__ __forceinline__ int tri(int b) { return b * NB - (b * (b - 1)) / 2; }

// ---------------------------------------------------------------------------
// Kernel 1: normalize rows (float4, 2 rows/wave), align partials (exact fp32),
// emit i8 quantized normalized rows: q = round(127 * x_hat).
// 1024 blocks x 256 threads.
// ---------------------------------------------------------------------------
__global__ __launch_bounds__(256) void prep_kernel(
    const float* __restrict__ users, const float* __restrict__ pos,
    signed char* __restrict__ U8, signed char* __restrict__ P8,
    double* __restrict__ alignPart)
{
    const int tid  = threadIdx.x;
    const int lane = tid & 63;
    const int w    = tid >> 6;
    const int l32  = lane & 31;
    const int half = lane >> 5;
    const int r    = blockIdx.x * 8 + w * 2 + half;

    const float4 u4 = ((const float4*)users)[r * 32 + l32];
    const float4 p4 = ((const float4*)pos )[r * 32 + l32];

    float su = u4.x*u4.x + u4.y*u4.y + u4.z*u4.z + u4.w*u4.w;
    float sp = p4.x*p4.x + p4.y*p4.y + p4.z*p4.z + p4.w*p4.w;
    for (int off = 16; off; off >>= 1) {
        su += __shfl_xor(su, off, 64);
        sp += __shfl_xor(sp, off, 64);
    }
    const float nu  = fmaxf(sqrtf(su), 1e-12f);
    const float npp = fmaxf(sqrtf(sp), 1e-12f);

    const float ux = u4.x / nu,  uy = u4.y / nu,  uz = u4.z / nu,  uw = u4.w / nu;
    const float px = p4.x / npp, py = p4.y / npp, pz = p4.z / npp, pw = p4.w / npp;

    // quantize to i8 (round-to-nearest), pack 4 bytes -> one int store
    union { signed char c[4]; int i; } qu, qp;
    qu.c[0] = (signed char)__float2int_rn(ux * 127.0f);
    qu.c[1] = (signed char)__float2int_rn(uy * 127.0f);
    qu.c[2] = (signed char)__float2int_rn(uz * 127.0f);
    qu.c[3] = (signed char)__float2int_rn(uw * 127.0f);
    qp.c[0] = (signed char)__float2int_rn(px * 127.0f);
    qp.c[1] = (signed char)__float2int_rn(py * 127.0f);
    qp.c[2] = (signed char)__float2int_rn(pz * 127.0f);
    qp.c[3] = (signed char)__float2int_rn(pw * 127.0f);
    ((int*)U8)[r * 32 + l32] = qu.i;
    ((int*)P8)[r * 32 + l32] = qp.i;

    const float dx = ux - px, dy = uy - py, dz = uz - pz, dw = uw - pw;
    float al = dx*dx + dy*dy + dz*dz + dw*dw;
    for (int off = 16; off; off >>= 1) al += __shfl_xor(al, off, 64);
    al += __shfl_xor(al, 32, 64);

    __shared__ float wsum[4];
    if (lane == 0) wsum[w] = al;
    __syncthreads();
    if (tid == 0)
        alignPart[blockIdx.x] = (double)wsum[0] + (double)wsum[1]
                              + (double)wsum[2] + (double)wsum[3];
}

// ---------------------------------------------------------------------------
// Kernel 2: 128x128 tile of G_int = Q*Q^T per block (bi<=bj, off-diag x2).
//   i8 path: rows are 128 B. LDS 32KB: A[128][128]i8 at 0, B at 16384 —
//   full K staged once per job (2 barriers). 4 waves (2x2), wave tile 64x64
//   = 2x2 frags of mfma_i32_32x32x32_i8 (acc i32x16, exact int arithmetic).
//   Swizzle: rows = 8 chunks of 16B; LDS chunk c of row r holds global chunk
//   c^(r&7) (pre-swizzled source, linear gload_lds dest; reads XOR back).
//   Epilogue: dot = v/127^2; sum exp2(C1*dot - C1) == exp(-2*d^2).
//   __launch_bounds__(256,4): 4 blocks/CU -> cross-block phase overlap.
// ---------------------------------------------------------------------------
__global__ __launch_bounds__(256, 4) void gram_kernel(
    const signed char* __restrict__ U8, const signed char* __restrict__ P8,
    double* __restrict__ Spart)
{
    __shared__ __align__(16) unsigned char smem[32768];
    __shared__ float wsum[4];

    const int bid = blockIdx.x;
    const int mat = bid >= JOBS_PER_MAT;
    const int t   = bid - (mat ? JOBS_PER_MAT : 0);

    int bi = (int)((NB + 0.5f) - sqrtf((NB + 0.5f) * (NB + 0.5f) - 2.0f * (float)t));
    if (bi > 0 && tri(bi) > t) --bi;
    if (tri(bi + 1) <= t) ++bi;
    const int bj = bi + (t - tri(bi));

    const char* __restrict__ Xb = (const char*)(mat ? P8 : U8);

    const int tid  = threadIdx.x;
    const int lane = tid & 63;
    const int w    = tid >> 6;

    // ---- staging: thread covers rows (tid>>3)+32i, linear chunk tid&7;
    //      global chunk pre-swizzled ^(row&7); row&7 == (tid>>3)&7 const. ----
    const int srow = tid >> 3;                       // 0..31
    const int gcOff = (((tid & 7) ^ (srow & 7)) << 4);
    const char* gA0 = Xb + (size_t)(bi * 128 + srow) * 128 + gcOff;
    const char* gB0 = Xb + (size_t)(bj * 128 + srow) * 128 + gcOff;
    unsigned char* lA0 = smem + w * 1024;            // wave-uniform dest base

#pragma unroll
    for (int i = 0; i < 4; ++i) {                    // 4 passes x 4KB each
        gload16(gA0 + i * 4096, lA0 + i * 4096);
        gload16(gB0 + i * 4096, lA0 + 16384 + i * 4096);
    }

    // ---- fragment geometry: 2x2 waves, wave tile 64x64, 32x32x32 frags ----
    const int wm = w >> 1, wn = w & 1;
    const int l32 = lane & 31;
    const int lh  = lane >> 5;                       // k-half (16B each)
    const unsigned cxor = (unsigned)(l32 & 7);       // row&7 for all frag rows
    const unsigned aRow0 = (unsigned)(wm * 64 + l32);
    const unsigned bRow0 = (unsigned)(wn * 64 + l32);

    i32x16 acc[2][2];
#pragma unroll
    for (int mi = 0; mi < 2; ++mi)
#pragma unroll
        for (int ni = 0; ni < 2; ++ni)
#pragma unroll
            for (int e = 0; e < 16; ++e)
                acc[mi][ni][e] = 0;

    __syncthreads();   // tiles staged (barrier implies vmcnt(0) drain)

#pragma unroll
    for (int ks = 0; ks < 4; ++ks) {                 // K = 4 x 32
        const unsigned c = (((unsigned)(ks * 2 + lh)) ^ cxor) << 4;
        i32x4 a[2], b[2];
#pragma unroll
        for (int mi = 0; mi < 2; ++mi)
            a[mi] = *reinterpret_cast<const i32x4*>(
                smem + (aRow0 + mi * 32) * 128 + c);
#pragma unroll
        for (int ni = 0; ni < 2; ++ni)
            b[ni] = *reinterpret_cast<const i32x4*>(
                smem + 16384 + (bRow0 + ni * 32) * 128 + c);
#pragma unroll
        for (int mi = 0; mi < 2; ++mi)
#pragma unroll
            for (int ni = 0; ni < 2; ++ni)
                acc[mi][ni] = __builtin_amdgcn_mfma_i32_32x32x32_i8(
                    a[mi], b[ni], acc[mi][ni], 0, 0, 0);
    }

    // ---- epilogue: dot = v/16129; sum exp2(C1*dot - C1) ----
    const float C1  = 4.0f * 1.4426950408889634f;    // 4*log2(e)
    const float C1s = C1 / 16129.0f;                 // scale for int dot
    float s0 = 0.f, s1 = 0.f, s2 = 0.f, s3 = 0.f;
#pragma unroll
    for (int mi = 0; mi < 2; ++mi)
#pragma unroll
        for (int ni = 0; ni < 2; ++ni) {
            const i32x16 v = acc[mi][ni];
#pragma unroll
            for (int e = 0; e < 16; e += 4) {
                s0 += fast_exp2(fmaf((float)v[e + 0], C1s, -C1));
                s1 += fast_exp2(fmaf((float)v[e + 1], C1s, -C1));
                s2 += fast_exp2(fmaf((float)v[e + 2], C1s, -C1));
                s3 += fast_exp2(fmaf((float)v[e + 3], C1s, -C1));
            }
        }

    const float s = waveReduceSum((s0 + s1) + (s2 + s3));
    if (lane == 0) wsum[w] = s;
    __syncthreads();
    if (tid == 0) {
        double bs = (double)wsum[0] + (double)wsum[1]
                  + (double)wsum[2] + (double)wsum[3];
        if (bi != bj) bs *= 2.0;     // off-diagonal tile counts twice in S_full
        Spart[bid] = bs;
    }
}

// ---------------------------------------------------------------------------
// Kernel 3: final reduction + loss formula. One block, 1024 threads.
// ---------------------------------------------------------------------------
__global__ __launch_bounds__(1024) void finalize_kernel(
    const double* __restrict__ alignPart, const double* __restrict__ Spart,
    float* __restrict__ out)
{
    const int tid = threadIdx.x;
    double a = 0.0, su = 0.0, sp = 0.0;
    for (int i = tid; i < 1024; i += 1024) a += alignPart[i];
    for (int i = tid; i < 2 * JOBS_PER_MAT; i += 1024) {
        const double v = Spart[i];
        if (i < JOBS_PER_MAT) su += v; else sp += v;
    }
    for (int off = 32; off; off >>= 1) {
        a  += __shfl_xor(a,  off, 64);
        su += __shfl_xor(su, off, 64);
        sp += __shfl_xor(sp, off, 64);
    }
    __shared__ double sh[3][16];
    const int lane = tid & 63, wid = tid >> 6;
    if (lane == 0) { sh[0][wid] = a; sh[1][wid] = su; sh[2][wid] = sp; }
    __syncthreads();
    if (tid == 0) {
        double A = 0.0, SU = 0.0, SP = 0.0;
        for (int i = 0; i < 16; ++i) { A += sh[0][i]; SU += sh[1][i]; SP += sh[2][i]; }
        const double Nd = 8192.0;
        const double npairs = Nd * (Nd - 1.0) * 0.5;
        const double align = A / Nd;
        const double mu = (SU - Nd) * 0.5 / npairs;
        const double mp = (SP - Nd) * 0.5 / npairs;
        const double uniform = 0.25 * (log(mu) + log(mp));
        out[0] = (float)((align + uniform) / 8192.0);
    }
}

// ---------------------------------------------------------------------------
extern "C" void kernel_launch(void* const* d_in, const int* in_sizes, int n_in,
                              void* d_out, int out_size, void* d_ws, size_t ws_size,
                              hipStream_t stream)
{
    const float* users = (const float*)d_in[0];
    const float* pos   = (const float*)d_in[1];
    // d_in[2] (neg_items) intentionally unused, matching the reference.
    float* out = (float*)d_out;

    char* ws = (char*)d_ws;
    signed char* U8 = (signed char*)ws;                    // 1 MiB
    signed char* P8 = (signed char*)(ws + 1048576);        // 1 MiB
    double* alignPart = (double*)(ws + 2097152);           // 1024 doubles
    double* Spart     = (double*)(ws + 2097152 + 8192);    // 4160 doubles

    hipLaunchKernelGGL(prep_kernel, dim3(1024), dim3(256), 0, stream,
                       users, pos, U8, P8, alignPart);
    hipLaunchKernelGGL(gram_kernel, dim3(2 * JOBS_PER_MAT), dim3(256), 0, stream,
                       U8, P8, Spart);
    hipLaunchKernelGGL(finalize_kernel, dim3(1), dim3(1024), 0, stream,
                       alignPart, Spart, out);
}